// Round 10
// baseline (78.200 us; speedup 1.0000x reference)
//
#include <hip/hip_runtime.h>

// Problem constants (B=2, T=2048, D=1024, N_EXP=8, TOP_K=2, CAP_FACTOR=1.25)
#define N_TOK   4096
#define DDIM    1024
#define N_EXP   8
#define CAP     1280                       // floor(2*1.25*4096/8), even, >=4
#define ROW     (N_EXP * CAP)              // 10240 floats per token row
#define CB_ELEMS (N_TOK * ROW)             // 41,943,040 floats per output tensor

typedef __attribute__((ext_vector_type(4))) float f32x4;

// ws layout:
//   [0,     4096)  : uint  pk[1024]   packed 4-bit expert ids, entry-major:
//                    entry i = k*4096 + t -> nibble (i&7) of word (i>>3)
//   [4096,  20480) : f32   p0[4096]   softmax weight, slot k=0
//   [20480, 36864) : f32   p1[4096]   softmax weight, slot k=1

// ---------------------------------------------------------------------------
// Kernel 1: router — 4096x8 GEMV, top-2, softmax over the 2 selected logits.
// One wave per token (4/block). Each block non-atomically stores its 4 tokens'
// expert nibbles as two 16-bit halfwords (disjoint across blocks). (R9-proven)
// ---------------------------------------------------------------------------
__global__ __launch_bounds__(256) void router_kernel(
    const float* __restrict__ x, const float* __restrict__ wg,
    unsigned int* __restrict__ pk,
    float* __restrict__ p0, float* __restrict__ p1)
{
    __shared__ int se0[4], se1[4];
    const int wave = threadIdx.x >> 6;
    const int lane = threadIdx.x & 63;
    const int t = blockIdx.x * 4 + wave;

    const float4* xt  = (const float4*)(x + (size_t)t * DDIM);  // 256 float4
    const float4* wg4 = (const float4*)wg;                      // [8][256]

    float acc[N_EXP];
#pragma unroll
    for (int e = 0; e < N_EXP; ++e) acc[e] = 0.f;

#pragma unroll
    for (int it = 0; it < 4; ++it) {
        const int d4 = lane + it * 64;
        const float4 xv = xt[d4];
#pragma unroll
        for (int e = 0; e < N_EXP; ++e) {
            const float4 wv = wg4[e * 256 + d4];
            acc[e] = fmaf(xv.x, wv.x,
                     fmaf(xv.y, wv.y,
                     fmaf(xv.z, wv.z,
                     fmaf(xv.w, wv.w, acc[e]))));
        }
    }

#pragma unroll
    for (int e = 0; e < N_EXP; ++e) {
#pragma unroll
        for (int off = 32; off >= 1; off >>= 1)
            acc[e] += __shfl_xor(acc[e], off, 64);
    }

    if (lane == 0) {
        // stable top-2 (strict >) matches jax.lax.top_k tie-breaking
        float v0 = -3.402823466e38f, v1 = -3.402823466e38f;
        int   i0 = 0, i1 = 0;
#pragma unroll
        for (int e = 0; e < N_EXP; ++e) {
            const float v = acc[e];
            if (v > v0)      { v1 = v0; i1 = i0; v0 = v; i0 = e; }
            else if (v > v1) { v1 = v;  i1 = e; }
        }
        const float ex  = expf(v1 - v0);
        const float inv = 1.f / (1.f + ex);
        p0[t] = inv;        // softmax([v0,v1])[0]
        p1[t] = ex * inv;   // softmax([v0,v1])[1]
        se0[wave] = i0;
        se1[wave] = i1;
    }
    __syncthreads();

    if (threadIdx.x == 0) {
        const int b = blockIdx.x;
        unsigned short* pks = (unsigned short*)pk;
        const unsigned short h0 = (unsigned short)(se0[0] | (se0[1] << 4) |
                                                   (se0[2] << 8) | (se0[3] << 12));
        const unsigned short h1 = (unsigned short)(se1[0] | (se1[1] << 4) |
                                                   (se1[2] << 8) | (se1[3] << 12));
        pks[b]        = h0;   // k=0 entries 4b..4b+3
        pks[1024 + b] = h1;   // k=1 entries 4096+4b..4096+4b+3
    }
}

// ---------------------------------------------------------------------------
// Kernel 2: fill — one contiguous 80 KB chunk per block.
// KEY ORDERING: the 17 pk loads are issued BEFORE the 20 zero stores.
// vmcnt is an in-order FIFO, so the count's waitcnt completes once the loads
// land, leaving the stores in flight -> the ~1000-cycle nibble count overlaps
// the ~8000-cycle store drain. ONE barrier total (already pre-drained), then
// the <=4 L2-warm fixups. Blocks [0,2048): cb rows; [2048,4096): mask rows.
// ---------------------------------------------------------------------------
__global__ __launch_bounds__(256) void fill_kernel(
    const unsigned int* __restrict__ pk, const float* __restrict__ p0,
    const float* __restrict__ p1, float* __restrict__ out)
{
    __shared__ int s_e[4], s_r[4];

    const int  b     = blockIdx.x;
    const bool is_cb = (b < 2048);
    const int  t0    = (is_cb ? b : (b - 2048)) * 2;   // token pair base

    const int wave = threadIdx.x >> 6;
    const int lane = threadIdx.x & 63;
    const int tt   = t0 + (wave >> 1);                 // this wave's token
    const int i    = (wave & 1) * N_TOK + tt;          // k-major entry index

    // ---- pk loads FIRST (L2-hot broadcast, 16 words/lane + 1 uniform) ------
    unsigned int w[16];
#pragma unroll
    for (int j = 0; j < 16; ++j) w[j] = pk[lane + j * 64];
    const unsigned int wi = pk[i >> 3];                // wave-uniform word

    // ---- streaming zero stores (drain while we count) ----------------------
    float* base = out + 8 + (is_cb ? 0 : (size_t)CB_ELEMS) + (size_t)t0 * ROW;
    f32x4* b4   = (f32x4*)base;                        // 5120 f32x4 = 80 KB
    const f32x4 z = {0.f, 0.f, 0.f, 0.f};
#pragma unroll
    for (int it = 0; it < 20; ++it)
        b4[threadIdx.x + it * 256] = z;

    // ---- rank = # prior k-major entries routed to the same expert ----------
    const int e = (int)((wi >> ((i & 7) * 4)) & 0xF);
    int cnt = 0;
#pragma unroll
    for (int j = 0; j < 16; ++j) {
        const int bi = (lane + j * 64) * 8;            // entry idx of nibble 0
#pragma unroll
        for (int s = 0; s < 8; ++s)
            cnt += (bi + s < i && (int)((w[j] >> (4 * s)) & 0xF) == e) ? 1 : 0;
    }
#pragma unroll
    for (int off = 32; off >= 1; off >>= 1)
        cnt += __shfl_xor(cnt, off, 64);
    if (lane == 0) { s_e[wave] = e; s_r[wave] = cnt; }

    __syncthreads();   // stores drained (overlapped); s_e/s_r visible

    // ---- fixup: <=4 entries, L2-warm ---------------------------------------
    if (threadIdx.x < 4) {
        const int r = s_r[threadIdx.x];
        if (r < CAP) {                                 // dropped tokens skipped
            const int   t2 = t0 + (threadIdx.x >> 1);
            const float wv = (threadIdx.x & 1) ? p1[t2] : p0[t2];
            const float v  = is_cb ? wv : ((wv != 0.f) ? 1.f : 0.f);
            base[(size_t)(t2 - t0) * ROW + s_e[threadIdx.x] * CAP + r] = v;
        }
    }

    // ---- block 0: used_capacity[8] (reuses the live w[] registers) ---------
    if (b == 0) {
#pragma unroll
        for (int q = 0; q < 2; ++q) {
            const int ee = wave * 2 + q;
            int c = 0;
#pragma unroll
            for (int j = 0; j < 16; ++j) {
#pragma unroll
                for (int s = 0; s < 8; ++s)
                    c += ((int)((w[j] >> (4 * s)) & 0xF) == ee) ? 1 : 0;
            }
#pragma unroll
            for (int off = 32; off >= 1; off >>= 1)
                c += __shfl_xor(c, off, 64);
            if (lane == 0) out[ee] = (float)min(c, CAP);
        }
    }
}

// ---------------------------------------------------------------------------
extern "C" void kernel_launch(void* const* d_in, const int* in_sizes, int n_in,
                              void* d_out, int out_size, void* d_ws, size_t ws_size,
                              hipStream_t stream)
{
    const float* x  = (const float*)d_in[0];   // [2,2048,1024] f32
    const float* wg = (const float*)d_in[1];   // [8,1024] f32
    float* out = (float*)d_out;                // [8] used | cb | mask

    char*         ws = (char*)d_ws;
    unsigned int* pk = (unsigned int*)(ws);
    float*        p0 = (float*)(ws + 4096);
    float*        p1 = (float*)(ws + 20480);

    router_kernel<<<N_TOK / 4, 256, 0, stream>>>(x, wg, pk, p0, p1);
    fill_kernel<<<4096, 256, 0, stream>>>(pk, p0, p1, out);
}